// Round 7
// baseline (119.529 us; speedup 1.0000x reference)
//
#include <hip/hip_runtime.h>
#include <hip/hip_bf16.h>
#include <math.h>
#include <stdint.h>

// Round 7: fat-wave GEMM — 2 waves/block (128 thr), each wave owns a
// 128x64 output tile (8x4 frags, 32-MFMA cluster per K=32 step, 12 ds_reads).
// Cuts LDS frag-read traffic 25% vs 4x(64x64). Ring-3 + counted vmcnt kept.
// Preps fused into one dispatch. ws image layout unchanged from round 5/6.

typedef __bf16 bf16_t;
typedef __attribute__((ext_vector_type(8))) __bf16 bf16x8;
typedef __attribute__((ext_vector_type(4))) float f32x4;

#define M_TOT 16384
#define E_DIM 768
#define F_DIM 3072

constexpr int BM = 128, BN = 128, BK = 64;
constexpr int MT = M_TOT / BM;    // 128
constexpr int NT = E_DIM / BN;    // 6
constexpr int KT = F_DIM / BK;    // 48
constexpr int KT2 = 2 * KT;       // 96 half-steps (K=32 each)
constexpr int HTILE = 8192;       // bytes per 128x32 bf16 half-tile image

// ws layout (identical to rounds 5/6)
constexpr size_t WS_A    = 0;                                    // MT*KT2 half-tiles
constexpr size_t WS_B    = WS_A + (size_t)MT * KT2 * HTILE;
constexpr size_t WS_NEED = WS_B + (size_t)NT * KT2 * HTILE;      // ~100.5 MiB

// ------------------------------------------------- fused prep (h + W2) ----
// blocks 0..767: (mt, seg) — h for 8 kt values each. blocks 768..1055: W2 tiles.
__global__ __launch_bounds__(256)
void ffq_prep(const float* __restrict__ x, const float* __restrict__ theta,
              const float* __restrict__ W1, const float* __restrict__ b1,
              const float* __restrict__ W2, char* __restrict__ ws)
{
    const int t = threadIdx.x;
    const int bid = blockIdx.x;

    if (bid < MT * 6) {
        // ---- h: block (mt, seg) covers kt = seg*8 .. seg*8+7 ----
        __shared__ __align__(16) char Hsm[16384];   // 2 x 8KB half-images
        const int mt = bid / 6, seg = bid % 6;
        const int row = t & 127, half = t >> 7;
        const int m = mt * BM + row;

        const float4 xv = *reinterpret_cast<const float4*>(x + (size_t)m * E_DIM);
        const float gx = cosf(xv.x) * cosf(theta[0]);
        const float gy = cosf(xv.y) * cosf(theta[1]);
        const float gz = cosf(xv.z) * cosf(theta[2]);
        const float gw = cosf(xv.w) * cosf(theta[3]);

        for (int kk = 0; kk < 8; ++kk) {
            const int kt = seg * 8 + kk;
            const int kb = kt * 64 + half * 32;
            #pragma unroll
            for (int o = 0; o < 4; ++o) {            // 4 octets of 8 k
                const int k0 = kb + o * 8;
                bf16x8 v;
                #pragma unroll
                for (int j = 0; j < 8; ++j) {
                    const int k = k0 + j;
                    float p = b1[k];
                    p = fmaf(gx, W1[k],              p);
                    p = fmaf(gy, W1[F_DIM + k],      p);
                    p = fmaf(gz, W1[2 * F_DIM + k],  p);
                    p = fmaf(gw, W1[3 * F_DIM + k],  p);
                    v[j] = (bf16_t)fmaxf(p, 0.0f);
                }
                const int slot = o ^ ((row >> 1) & 3);
                *reinterpret_cast<bf16x8*>(&Hsm[half * HTILE + row * 64 + slot * 16]) = v;
            }
            __syncthreads();
            char* dst = ws + WS_A + (size_t)(mt * KT + kt) * 2 * HTILE;
            #pragma unroll
            for (int r = 0; r < 4; ++r) {
                const int c = r * 256 + t;
                *reinterpret_cast<bf16x8*>(dst + (size_t)c * 16) =
                    *reinterpret_cast<const bf16x8*>(&Hsm[c * 16]);
            }
            __syncthreads();
        }
    } else {
        // ---- W2 tile (kt,nt) -> bf16 swizzled half-tile pair ----
        __shared__ float Wf[64][132];
        const int idx = bid - MT * 6;
        const int kt = idx / NT, nt = idx % NT;
        const int r  = t >> 5;
        const int c4 = (t & 31) << 2;
        #pragma unroll
        for (int i = 0; i < 8; ++i) {
            const int row = i * 8 + r;
            const float4 v = *reinterpret_cast<const float4*>(
                &W2[(size_t)(kt * 64 + row) * E_DIM + nt * 128 + c4]);
            Wf[row][c4] = v.x; Wf[row][c4 + 1] = v.y;
            Wf[row][c4 + 2] = v.z; Wf[row][c4 + 3] = v.w;
        }
        __syncthreads();
        char* dst = ws + WS_B + (size_t)(nt * KT + kt) * 2 * HTILE;
        #pragma unroll
        for (int cc = 0; cc < 4; ++cc) {
            const int c    = cc * 256 + t;
            const int half = c >> 9;
            const int q    = c & 511;
            const int n    = q >> 2;
            const int slot = q & 3;
            const int oc   = slot ^ ((n >> 1) & 3);
            bf16x8 v;
            #pragma unroll
            for (int j = 0; j < 8; ++j) v[j] = (bf16_t)Wf[half * 32 + oc * 8 + j][n];
            *reinterpret_cast<bf16x8*>(dst + (size_t)c * 16) = v;
        }
    }
}

// ---------------------------------------------------------------- GEMM ----
// 128 threads = 2 waves; wave w owns rows 0..127 x cols w*64..w*64+63.
__global__ __launch_bounds__(128, 2)
void ffq_gemm(const char* __restrict__ ws, const float* __restrict__ b2,
              float* __restrict__ out)
{
    __shared__ __align__(16) char Abuf[3][HTILE];   // 24KB
    __shared__ __align__(16) char Bbuf[3][HTILE];   // 24KB

    const int t = threadIdx.x;
    const int lane = t & 63, wid = t >> 6;          // wid = 0,1

    // XCD-coherent mapping: each XCD owns 16 m-panels x all 6 n-tiles
    const int bid = blockIdx.x;                     // 768 = 8 * 96
    const int xcd = bid & 7;
    const int i   = bid >> 3;
    const int mt  = xcd * 16 + (i & 15);
    const int nt  = i >> 4;
    const int m0 = mt * BM, n0 = nt * BN;

    const char* srcA = ws + WS_A + (size_t)mt * KT2 * HTILE;
    const char* srcB = ws + WS_B + (size_t)nt * KT2 * HTILE;

    const int fr = lane & 15, fg = lane >> 4;

    f32x4 acc[8][4] = {};

    // one STAGE = 8 global_load_lds per thread (4 A + 4 B), 16KB total
    #define STAGE(kk, buf) do {                                                 \
        const char* sa_ = srcA + (size_t)(kk) * HTILE;                          \
        const char* sb_ = srcB + (size_t)(kk) * HTILE;                          \
        _Pragma("unroll")                                                       \
        for (int r_ = 0; r_ < 4; ++r_) {                                        \
            const int off_ = r_ * 2048 + t * 16;                                \
            __builtin_amdgcn_global_load_lds(                                   \
                (const __attribute__((address_space(1))) void*)(sa_ + off_),    \
                (__attribute__((address_space(3))) void*)(&Abuf[buf][0] + off_),\
                16, 0, 0);                                                      \
            __builtin_amdgcn_global_load_lds(                                   \
                (const __attribute__((address_space(1))) void*)(sb_ + off_),    \
                (__attribute__((address_space(3))) void*)(&Bbuf[buf][0] + off_),\
                16, 0, 0);                                                      \
        } } while (0)

    #define COMPUTE(buf) do {                                                   \
        const char* ab_ = &Abuf[buf][0];                                        \
        const char* bb_ = &Bbuf[buf][0];                                        \
        bf16x8 af[8], bfr[4];                                                   \
        _Pragma("unroll")                                                       \
        for (int mi = 0; mi < 8; ++mi) {                                        \
            const int ra = mi * 16 + fr;                                        \
            const int sl = fg ^ ((ra >> 1) & 3);                                \
            af[mi] = *reinterpret_cast<const bf16x8*>(ab_ + ra * 64 + sl * 16); \
        }                                                                       \
        _Pragma("unroll")                                                       \
        for (int ni = 0; ni < 4; ++ni) {                                        \
            const int rb = wid * 64 + ni * 16 + fr;                             \
            const int sl = fg ^ ((rb >> 1) & 3);                                \
            bfr[ni] = *reinterpret_cast<const bf16x8*>(bb_ + rb * 64 + sl * 16);\
        }                                                                       \
        __builtin_amdgcn_s_setprio(1);                                          \
        _Pragma("unroll")                                                       \
        for (int mi = 0; mi < 8; ++mi)                                          \
            _Pragma("unroll")                                                   \
            for (int ni = 0; ni < 4; ++ni)                                      \
                acc[mi][ni] = __builtin_amdgcn_mfma_f32_16x16x32_bf16(          \
                    af[mi], bfr[ni], acc[mi][ni], 0, 0, 0);                     \
        __builtin_amdgcn_s_setprio(0);                                          \
    } while (0)

    STAGE(0, 0);
    STAGE(1, 1);

    int buf = 0;
    for (int k2 = 0; k2 < KT2 - 2; ++k2) {
        // tile k2's 8 loads done; tile k2+1's 8 stay in flight
        asm volatile("s_waitcnt vmcnt(8)" ::: "memory");
        __builtin_amdgcn_s_barrier();
        __builtin_amdgcn_sched_barrier(0);
        const int nxt = buf + 2 >= 3 ? buf - 1 : buf + 2;   // (buf+2)%3
        STAGE(k2 + 2, nxt);
        COMPUTE(buf);
        buf = buf + 1 >= 3 ? 0 : buf + 1;
    }
    // tail 1: tile KT2-2 (KT2-1 still in flight)
    asm volatile("s_waitcnt vmcnt(8)" ::: "memory");
    __builtin_amdgcn_s_barrier();
    __builtin_amdgcn_sched_barrier(0);
    COMPUTE(buf);
    buf = buf + 1 >= 3 ? 0 : buf + 1;
    // tail 2: drain
    asm volatile("s_waitcnt vmcnt(0)" ::: "memory");
    __builtin_amdgcn_s_barrier();
    __builtin_amdgcn_sched_barrier(0);
    COMPUTE(buf);

    #undef STAGE
    #undef COMPUTE

    // epilogue (C/D: col=lane&15, row=(lane>>4)*4+r)
    #pragma unroll
    for (int ni = 0; ni < 4; ++ni) {
        const int col = n0 + wid * 64 + ni * 16 + fr;
        const float bias = b2[col];
        #pragma unroll
        for (int mi = 0; mi < 8; ++mi) {
            #pragma unroll
            for (int rr = 0; rr < 4; ++rr) {
                const int ro = m0 + mi * 16 + fg * 4 + rr;
                out[(size_t)ro * E_DIM + col] = acc[mi][ni][rr] + bias;
            }
        }
    }
}

// ------------------------------------------- fallback: round-1 fused ------
__global__ __launch_bounds__(256, 2)
void ffq_fused(const float* __restrict__ x, const float* __restrict__ theta,
               const float* __restrict__ W1, const float* __restrict__ b1,
               const float* __restrict__ W2, const float* __restrict__ b2,
               float* __restrict__ out)
{
    __shared__ bf16_t Asm[BM][BK];
    __shared__ bf16_t Bsm[BN][BK];
    __shared__ float  gsm[BM][4];
    __shared__ float  b2sm[BN];

    const int t = threadIdx.x;
    const int lane = t & 63, wid = t >> 6;
    const int bid = blockIdx.x;
    const int swz = (bid & 7) * (MT * NT / 8) + (bid >> 3);
    const int ntile = swz / MT, mtile = swz % MT;
    const int m0 = mtile * BM, n0 = ntile * BN;

    const float c0 = cosf(theta[0]), c1 = cosf(theta[1]);
    const float c2 = cosf(theta[2]), c3 = cosf(theta[3]);
    if (t < BM) {
        const float4 xv = *reinterpret_cast<const float4*>(x + (size_t)(m0 + t) * E_DIM);
        gsm[t][0] = cosf(xv.x) * c0; gsm[t][1] = cosf(xv.y) * c1;
        gsm[t][2] = cosf(xv.z) * c2; gsm[t][3] = cosf(xv.w) * c3;
    } else {
        const int n = t - 128;
        b2sm[n] = b2[n0 + n];
    }
    __syncthreads();

    const int rg = t >> 3, kg = t & 7;
    const int nB = t & 127, kh = t >> 7;
    const int wr = wid >> 1, wc = wid & 1;
    const int fr = lane & 15, fg = lane >> 4;

    f32x4 acc[4][4] = {};

    for (int k0 = 0; k0 < F_DIM; k0 += BK) {
        {
            const int kA = k0 + (kg << 3);
            float w1v[4][8], b1v[8];
            #pragma unroll
            for (int q = 0; q < 4; ++q) {
                const float4 lo = *reinterpret_cast<const float4*>(&W1[q * F_DIM + kA]);
                const float4 hi = *reinterpret_cast<const float4*>(&W1[q * F_DIM + kA + 4]);
                w1v[q][0] = lo.x; w1v[q][1] = lo.y; w1v[q][2] = lo.z; w1v[q][3] = lo.w;
                w1v[q][4] = hi.x; w1v[q][5] = hi.y; w1v[q][6] = hi.z; w1v[q][7] = hi.w;
            }
            {
                const float4 lo = *reinterpret_cast<const float4*>(&b1[kA]);
                const float4 hi = *reinterpret_cast<const float4*>(&b1[kA + 4]);
                b1v[0] = lo.x; b1v[1] = lo.y; b1v[2] = lo.z; b1v[3] = lo.w;
                b1v[4] = hi.x; b1v[5] = hi.y; b1v[6] = hi.z; b1v[7] = hi.w;
            }
            #pragma unroll
            for (int r = 0; r < 4; ++r) {
                const int row = (rg << 2) + r;
                const float4 g = *reinterpret_cast<const float4*>(&gsm[row][0]);
                bf16x8 v;
                #pragma unroll
                for (int kk = 0; kk < 8; ++kk) {
                    float p = b1v[kk];
                    p = fmaf(g.x, w1v[0][kk], p);
                    p = fmaf(g.y, w1v[1][kk], p);
                    p = fmaf(g.z, w1v[2][kk], p);
                    p = fmaf(g.w, w1v[3][kk], p);
                    v[kk] = (bf16_t)fmaxf(p, 0.0f);
                }
                *reinterpret_cast<bf16x8*>(&Asm[row][(kg ^ (row & 7)) << 3]) = v;
            }
        }
        {
            const float* w2p = W2 + (size_t)(k0 + (kh << 5)) * E_DIM + n0 + nB;
            float bv[32];
            #pragma unroll
            for (int kk = 0; kk < 32; ++kk) bv[kk] = w2p[kk * E_DIM];
            #pragma unroll
            for (int o = 0; o < 4; ++o) {
                bf16x8 v;
                #pragma unroll
                for (int j = 0; j < 8; ++j) v[j] = (bf16_t)bv[(o << 3) + j];
                *reinterpret_cast<bf16x8*>(&Bsm[nB][(((kh << 2) + o) ^ (nB & 7)) << 3]) = v;
            }
        }
        __syncthreads();
        #pragma unroll
        for (int ks = 0; ks < 2; ++ks) {
            const int kob = (ks << 2) + fg;
            bf16x8 af[4], bfr[4];
            #pragma unroll
            for (int mi = 0; mi < 4; ++mi) {
                const int row = (wr << 6) + (mi << 4) + fr;
                af[mi] = *reinterpret_cast<const bf16x8*>(&Asm[row][(kob ^ (row & 7)) << 3]);
            }
            #pragma unroll
            for (int ni = 0; ni < 4; ++ni) {
                const int rn = (wc << 6) + (ni << 4) + fr;
                bfr[ni] = *reinterpret_cast<const bf16x8*>(&Bsm[rn][(kob ^ (rn & 7)) << 3]);
            }
            #pragma unroll
            for (int mi = 0; mi < 4; ++mi)
                #pragma unroll
                for (int ni = 0; ni < 4; ++ni)
                    acc[mi][ni] = __builtin_amdgcn_mfma_f32_16x16x32_bf16(
                        af[mi], bfr[ni], acc[mi][ni], 0, 0, 0);
        }
        __syncthreads();
    }

    #pragma unroll
    for (int mi = 0; mi < 4; ++mi)
        #pragma unroll
        for (int ni = 0; ni < 4; ++ni) {
            const int col  = n0 + (wc << 6) + (ni << 4) + fr;
            const float bias = b2sm[(wc << 6) + (ni << 4) + fr];
            #pragma unroll
            for (int r = 0; r < 4; ++r) {
                const int row = m0 + (wr << 6) + (mi << 4) + (fg << 2) + r;
                out[(size_t)row * E_DIM + col] = acc[mi][ni][r] + bias;
            }
        }
}

// -------------------------------------------------------------- launch ----
extern "C" void kernel_launch(void* const* d_in, const int* in_sizes, int n_in,
                              void* d_out, int out_size, void* d_ws, size_t ws_size,
                              hipStream_t stream) {
    const float* x     = (const float*)d_in[0];
    const float* theta = (const float*)d_in[1];
    const float* W1    = (const float*)d_in[2];
    const float* b1    = (const float*)d_in[3];
    const float* W2    = (const float*)d_in[4];
    const float* b2    = (const float*)d_in[5];
    float* out = (float*)d_out;

    if (ws_size >= WS_NEED) {
        hipLaunchKernelGGL(ffq_prep, dim3(MT * 6 + KT * NT), dim3(256), 0, stream,
                           x, theta, W1, b1, W2, (char*)d_ws);
        hipLaunchKernelGGL(ffq_gemm, dim3(MT * NT), dim3(128), 0, stream,
                           (const char*)d_ws, b2, out);
    } else {
        hipLaunchKernelGGL(ffq_fused, dim3(MT * NT), dim3(256), 0, stream,
                           x, theta, W1, b1, W2, b2, out);
    }
}

// Round 8
// 108.833 us; speedup vs baseline: 1.0983x; 1.0983x over previous
//
#include <hip/hip_runtime.h>
#include <hip/hip_bf16.h>
#include <math.h>
#include <stdint.h>

// Round 8: back to 4-wave 128x128 blocks (round-6 geometry) + register
// fragment double-buffer. Ring-2 LDS (32KB): at iter k, MFMA runs on tile-k
// frags held in VGPRs while ds_reads fetch tile-k+1 frags and global_load_lds
// stages tile k+2 over tile k's LDS. One raw s_barrier per iter; vmcnt(0)
// waits 1-iter-old loads (near-free); end-of-iter lgkmcnt(0) protects the
// buffer overwrite. Prep = fused single dispatch (round 7). ws layout as r5/6.

typedef __bf16 bf16_t;
typedef __attribute__((ext_vector_type(8))) __bf16 bf16x8;
typedef __attribute__((ext_vector_type(4))) float f32x4;

#define M_TOT 16384
#define E_DIM 768
#define F_DIM 3072

constexpr int BM = 128, BN = 128, BK = 64;
constexpr int MT = M_TOT / BM;    // 128
constexpr int NT = E_DIM / BN;    // 6
constexpr int KT = F_DIM / BK;    // 48
constexpr int KT2 = 2 * KT;       // 96 half-steps (K=32 each)
constexpr int HTILE = 8192;       // bytes per 128x32 bf16 half-tile image

// ws layout (identical to rounds 5-7)
constexpr size_t WS_A    = 0;                                    // MT*KT2 half-tiles
constexpr size_t WS_B    = WS_A + (size_t)MT * KT2 * HTILE;
constexpr size_t WS_NEED = WS_B + (size_t)NT * KT2 * HTILE;      // ~100.5 MiB

// ------------------------------------------------- fused prep (h + W2) ----
__global__ __launch_bounds__(256)
void ffq_prep(const float* __restrict__ x, const float* __restrict__ theta,
              const float* __restrict__ W1, const float* __restrict__ b1,
              const float* __restrict__ W2, char* __restrict__ ws)
{
    const int t = threadIdx.x;
    const int bid = blockIdx.x;

    if (bid < MT * 6) {
        // ---- h: block (mt, seg) covers kt = seg*8 .. seg*8+7 ----
        __shared__ __align__(16) char Hsm[16384];   // 2 x 8KB half-images
        const int mt = bid / 6, seg = bid % 6;
        const int row = t & 127, half = t >> 7;
        const int m = mt * BM + row;

        const float4 xv = *reinterpret_cast<const float4*>(x + (size_t)m * E_DIM);
        const float gx = cosf(xv.x) * cosf(theta[0]);
        const float gy = cosf(xv.y) * cosf(theta[1]);
        const float gz = cosf(xv.z) * cosf(theta[2]);
        const float gw = cosf(xv.w) * cosf(theta[3]);

        for (int kk = 0; kk < 8; ++kk) {
            const int kt = seg * 8 + kk;
            const int kb = kt * 64 + half * 32;
            #pragma unroll
            for (int o = 0; o < 4; ++o) {            // 4 octets of 8 k
                const int k0 = kb + o * 8;
                bf16x8 v;
                #pragma unroll
                for (int j = 0; j < 8; ++j) {
                    const int k = k0 + j;
                    float p = b1[k];
                    p = fmaf(gx, W1[k],              p);
                    p = fmaf(gy, W1[F_DIM + k],      p);
                    p = fmaf(gz, W1[2 * F_DIM + k],  p);
                    p = fmaf(gw, W1[3 * F_DIM + k],  p);
                    v[j] = (bf16_t)fmaxf(p, 0.0f);
                }
                const int slot = o ^ ((row >> 1) & 3);
                *reinterpret_cast<bf16x8*>(&Hsm[half * HTILE + row * 64 + slot * 16]) = v;
            }
            __syncthreads();
            char* dst = ws + WS_A + (size_t)(mt * KT + kt) * 2 * HTILE;
            #pragma unroll
            for (int r = 0; r < 4; ++r) {
                const int c = r * 256 + t;
                *reinterpret_cast<bf16x8*>(dst + (size_t)c * 16) =
                    *reinterpret_cast<const bf16x8*>(&Hsm[c * 16]);
            }
            __syncthreads();
        }
    } else {
        // ---- W2 tile (kt,nt) -> bf16 swizzled half-tile pair ----
        __shared__ float Wf[64][132];
        const int idx = bid - MT * 6;
        const int kt = idx / NT, nt = idx % NT;
        const int r  = t >> 5;
        const int c4 = (t & 31) << 2;
        #pragma unroll
        for (int i = 0; i < 8; ++i) {
            const int row = i * 8 + r;
            const float4 v = *reinterpret_cast<const float4*>(
                &W2[(size_t)(kt * 64 + row) * E_DIM + nt * 128 + c4]);
            Wf[row][c4] = v.x; Wf[row][c4 + 1] = v.y;
            Wf[row][c4 + 2] = v.z; Wf[row][c4 + 3] = v.w;
        }
        __syncthreads();
        char* dst = ws + WS_B + (size_t)(nt * KT + kt) * 2 * HTILE;
        #pragma unroll
        for (int cc = 0; cc < 4; ++cc) {
            const int c    = cc * 256 + t;
            const int half = c >> 9;
            const int q    = c & 511;
            const int n    = q >> 2;
            const int slot = q & 3;
            const int oc   = slot ^ ((n >> 1) & 3);
            bf16x8 v;
            #pragma unroll
            for (int j = 0; j < 8; ++j) v[j] = (bf16_t)Wf[half * 32 + oc * 8 + j][n];
            *reinterpret_cast<bf16x8*>(dst + (size_t)c * 16) = v;
        }
    }
}

// ---------------------------------------------------------------- GEMM ----
__global__ __launch_bounds__(256, 3)
void ffq_gemm(const char* __restrict__ ws, const float* __restrict__ b2,
              float* __restrict__ out)
{
    __shared__ __align__(16) char Abuf[2][HTILE];   // 16KB
    __shared__ __align__(16) char Bbuf[2][HTILE];   // 16KB

    const int t = threadIdx.x;
    const int lane = t & 63, wid = t >> 6;

    // XCD-coherent mapping: each XCD owns 16 m-panels x all 6 n-tiles
    const int bid = blockIdx.x;                     // 768 = 8 * 96
    const int xcd = bid & 7;
    const int i   = bid >> 3;
    const int mt  = xcd * 16 + (i & 15);
    const int nt  = i >> 4;
    const int m0 = mt * BM, n0 = nt * BN;

    const char* srcA = ws + WS_A + (size_t)mt * KT2 * HTILE;
    const char* srcB = ws + WS_B + (size_t)nt * KT2 * HTILE;

    const int wr = wid >> 1, wc = wid & 1;
    const int fr = lane & 15, fg = lane >> 4;

    f32x4 acc[4][4] = {};
    bf16x8 fa0[4], fb0[4], fa1[4], fb1[4];

    // one STAGE = 4 global_load_lds per thread (2 A + 2 B), 16KB total
    #define STAGE(kk, buf) do {                                                 \
        const char* sa_ = srcA + (size_t)(kk) * HTILE;                          \
        const char* sb_ = srcB + (size_t)(kk) * HTILE;                          \
        _Pragma("unroll")                                                       \
        for (int r_ = 0; r_ < 2; ++r_) {                                        \
            const int off_ = r_ * 4096 + t * 16;                                \
            __builtin_amdgcn_global_load_lds(                                   \
                (const __attribute__((address_space(1))) void*)(sa_ + off_),    \
                (__attribute__((address_space(3))) void*)(&Abuf[buf][0] + off_),\
                16, 0, 0);                                                      \
            __builtin_amdgcn_global_load_lds(                                   \
                (const __attribute__((address_space(1))) void*)(sb_ + off_),    \
                (__attribute__((address_space(3))) void*)(&Bbuf[buf][0] + off_),\
                16, 0, 0);                                                      \
        } } while (0)

    // read one K=32 step's fragments from LDS buffer into regs
    #define RDFRAGS(FA, FB, buf) do {                                           \
        const char* ab_ = &Abuf[buf][0];                                        \
        const char* bb_ = &Bbuf[buf][0];                                        \
        _Pragma("unroll")                                                       \
        for (int mi = 0; mi < 4; ++mi) {                                        \
            const int ra = wr * 64 + mi * 16 + fr;                              \
            const int sl = fg ^ ((ra >> 1) & 3);                                \
            FA[mi] = *reinterpret_cast<const bf16x8*>(ab_ + ra * 64 + sl * 16); \
        }                                                                       \
        _Pragma("unroll")                                                       \
        for (int ni = 0; ni < 4; ++ni) {                                        \
            const int rb = wc * 64 + ni * 16 + fr;                              \
            const int sl = fg ^ ((rb >> 1) & 3);                                \
            FB[ni] = *reinterpret_cast<const bf16x8*>(bb_ + rb * 64 + sl * 16); \
        } } while (0)

    #define MFMA16(FA, FB) do {                                                 \
        __builtin_amdgcn_s_setprio(1);                                          \
        _Pragma("unroll")                                                       \
        for (int mi = 0; mi < 4; ++mi)                                          \
            _Pragma("unroll")                                                   \
            for (int ni = 0; ni < 4; ++ni)                                      \
                acc[mi][ni] = __builtin_amdgcn_mfma_f32_16x16x32_bf16(          \
                    FA[mi], FB[ni], acc[mi][ni], 0, 0, 0);                      \
        __builtin_amdgcn_s_setprio(0);                                          \
    } while (0)

    // ITER: sync; stage tile k+2 over tile k's buf; read tile k+1 frags;
    //       MFMA on tile k's regs; drain own ds_reads before next barrier.
    #define ITER(k, CUR, FA, FB, NFA, NFB, DOSTAGE, DOREAD) do {                \
        asm volatile("s_waitcnt vmcnt(0)" ::: "memory");                        \
        __builtin_amdgcn_s_barrier();                                           \
        __builtin_amdgcn_sched_barrier(0);                                      \
        if (DOSTAGE) STAGE((k) + 2, CUR);                                       \
        if (DOREAD)  RDFRAGS(NFA, NFB, (CUR) ^ 1);                              \
        MFMA16(FA, FB);                                                         \
        asm volatile("s_waitcnt lgkmcnt(0)" ::: "memory");                      \
        __builtin_amdgcn_sched_barrier(0);                                      \
    } while (0)

    // prologue: tile0 -> buf0 -> regs; tile1 -> buf1 (in flight)
    STAGE(0, 0);
    __syncthreads();
    RDFRAGS(fa0, fb0, 0);
    STAGE(1, 1);
    asm volatile("s_waitcnt lgkmcnt(0)" ::: "memory");
    __builtin_amdgcn_sched_barrier(0);

    for (int p = 0; p < KT2 / 2 - 1; ++p) {          // k = 0..93
        ITER(2 * p,     0, fa0, fb0, fa1, fb1, true, true);
        ITER(2 * p + 1, 1, fa1, fb1, fa0, fb0, true, true);
    }
    ITER(KT2 - 2, 0, fa0, fb0, fa1, fb1, false, true);   // k = 94
    ITER(KT2 - 1, 1, fa1, fb1, fa0, fb0, false, false);  // k = 95

    #undef STAGE
    #undef RDFRAGS
    #undef MFMA16
    #undef ITER

    // epilogue (C/D: col=lane&15, row=(lane>>4)*4+r)
    #pragma unroll
    for (int ni = 0; ni < 4; ++ni) {
        const int col = n0 + wc * 64 + ni * 16 + fr;
        const float bias = b2[col];
        #pragma unroll
        for (int mi = 0; mi < 4; ++mi) {
            #pragma unroll
            for (int rr = 0; rr < 4; ++rr) {
                const int ro = m0 + wr * 64 + mi * 16 + fg * 4 + rr;
                out[(size_t)ro * E_DIM + col] = acc[mi][ni][rr] + bias;
            }
        }
    }
}

// ------------------------------------------- fallback: round-1 fused ------
__global__ __launch_bounds__(256, 2)
void ffq_fused(const float* __restrict__ x, const float* __restrict__ theta,
               const float* __restrict__ W1, const float* __restrict__ b1,
               const float* __restrict__ W2, const float* __restrict__ b2,
               float* __restrict__ out)
{
    __shared__ bf16_t Asm[BM][BK];
    __shared__ bf16_t Bsm[BN][BK];
    __shared__ float  gsm[BM][4];
    __shared__ float  b2sm[BN];

    const int t = threadIdx.x;
    const int lane = t & 63, wid = t >> 6;
    const int bid = blockIdx.x;
    const int swz = (bid & 7) * (MT * NT / 8) + (bid >> 3);
    const int ntile = swz / MT, mtile = swz % MT;
    const int m0 = mtile * BM, n0 = ntile * BN;

    const float c0 = cosf(theta[0]), c1 = cosf(theta[1]);
    const float c2 = cosf(theta[2]), c3 = cosf(theta[3]);
    if (t < BM) {
        const float4 xv = *reinterpret_cast<const float4*>(x + (size_t)(m0 + t) * E_DIM);
        gsm[t][0] = cosf(xv.x) * c0; gsm[t][1] = cosf(xv.y) * c1;
        gsm[t][2] = cosf(xv.z) * c2; gsm[t][3] = cosf(xv.w) * c3;
    } else {
        const int n = t - 128;
        b2sm[n] = b2[n0 + n];
    }
    __syncthreads();

    const int rg = t >> 3, kg = t & 7;
    const int nB = t & 127, kh = t >> 7;
    const int wr = wid >> 1, wc = wid & 1;
    const int fr = lane & 15, fg = lane >> 4;

    f32x4 acc[4][4] = {};

    for (int k0 = 0; k0 < F_DIM; k0 += BK) {
        {
            const int kA = k0 + (kg << 3);
            float w1v[4][8], b1v[8];
            #pragma unroll
            for (int q = 0; q < 4; ++q) {
                const float4 lo = *reinterpret_cast<const float4*>(&W1[q * F_DIM + kA]);
                const float4 hi = *reinterpret_cast<const float4*>(&W1[q * F_DIM + kA + 4]);
                w1v[q][0] = lo.x; w1v[q][1] = lo.y; w1v[q][2] = lo.z; w1v[q][3] = lo.w;
                w1v[q][4] = hi.x; w1v[q][5] = hi.y; w1v[q][6] = hi.z; w1v[q][7] = hi.w;
            }
            {
                const float4 lo = *reinterpret_cast<const float4*>(&b1[kA]);
                const float4 hi = *reinterpret_cast<const float4*>(&b1[kA + 4]);
                b1v[0] = lo.x; b1v[1] = lo.y; b1v[2] = lo.z; b1v[3] = lo.w;
                b1v[4] = hi.x; b1v[5] = hi.y; b1v[6] = hi.z; b1v[7] = hi.w;
            }
            #pragma unroll
            for (int r = 0; r < 4; ++r) {
                const int row = (rg << 2) + r;
                const float4 g = *reinterpret_cast<const float4*>(&gsm[row][0]);
                bf16x8 v;
                #pragma unroll
                for (int kk = 0; kk < 8; ++kk) {
                    float p = b1v[kk];
                    p = fmaf(g.x, w1v[0][kk], p);
                    p = fmaf(g.y, w1v[1][kk], p);
                    p = fmaf(g.z, w1v[2][kk], p);
                    p = fmaf(g.w, w1v[3][kk], p);
                    v[kk] = (bf16_t)fmaxf(p, 0.0f);
                }
                *reinterpret_cast<bf16x8*>(&Asm[row][(kg ^ (row & 7)) << 3]) = v;
            }
        }
        {
            const float* w2p = W2 + (size_t)(k0 + (kh << 5)) * E_DIM + n0 + nB;
            float bv[32];
            #pragma unroll
            for (int kk = 0; kk < 32; ++kk) bv[kk] = w2p[kk * E_DIM];
            #pragma unroll
            for (int o = 0; o < 4; ++o) {
                bf16x8 v;
                #pragma unroll
                for (int j = 0; j < 8; ++j) v[j] = (bf16_t)bv[(o << 3) + j];
                *reinterpret_cast<bf16x8*>(&Bsm[nB][(((kh << 2) + o) ^ (nB & 7)) << 3]) = v;
            }
        }
        __syncthreads();
        #pragma unroll
        for (int ks = 0; ks < 2; ++ks) {
            const int kob = (ks << 2) + fg;
            bf16x8 af[4], bfr[4];
            #pragma unroll
            for (int mi = 0; mi < 4; ++mi) {
                const int row = (wr << 6) + (mi << 4) + fr;
                af[mi] = *reinterpret_cast<const bf16x8*>(&Asm[row][(kob ^ (row & 7)) << 3]);
            }
            #pragma unroll
            for (int ni = 0; ni < 4; ++ni) {
                const int rn = (wc << 6) + (ni << 4) + fr;
                bfr[ni] = *reinterpret_cast<const bf16x8*>(&Bsm[rn][(kob ^ (rn & 7)) << 3]);
            }
            #pragma unroll
            for (int mi = 0; mi < 4; ++mi)
                #pragma unroll
                for (int ni = 0; ni < 4; ++ni)
                    acc[mi][ni] = __builtin_amdgcn_mfma_f32_16x16x32_bf16(
                        af[mi], bfr[ni], acc[mi][ni], 0, 0, 0);
        }
        __syncthreads();
    }

    #pragma unroll
    for (int mi = 0; mi < 4; ++mi)
        #pragma unroll
        for (int ni = 0; ni < 4; ++ni) {
            const int col  = n0 + (wc << 6) + (ni << 4) + fr;
            const float bias = b2sm[(wc << 6) + (ni << 4) + fr];
            #pragma unroll
            for (int r = 0; r < 4; ++r) {
                const int row = m0 + (wr << 6) + (mi << 4) + (fg << 2) + r;
                out[(size_t)row * E_DIM + col] = acc[mi][ni][r] + bias;
            }
        }
}

// -------------------------------------------------------------- launch ----
extern "C" void kernel_launch(void* const* d_in, const int* in_sizes, int n_in,
                              void* d_out, int out_size, void* d_ws, size_t ws_size,
                              hipStream_t stream) {
    const float* x     = (const float*)d_in[0];
    const float* theta = (const float*)d_in[1];
    const float* W1    = (const float*)d_in[2];
    const float* b1    = (const float*)d_in[3];
    const float* W2    = (const float*)d_in[4];
    const float* b2    = (const float*)d_in[5];
    float* out = (float*)d_out;

    if (ws_size >= WS_NEED) {
        hipLaunchKernelGGL(ffq_prep, dim3(MT * 6 + KT * NT), dim3(256), 0, stream,
                           x, theta, W1, b1, W2, (char*)d_ws);
        hipLaunchKernelGGL(ffq_gemm, dim3(MT * NT), dim3(256), 0, stream,
                           (const char*)d_ws, b2, out);
    } else {
        hipLaunchKernelGGL(ffq_fused, dim3(MT * NT), dim3(256), 0, stream,
                           x, theta, W1, b1, W2, b2, out);
    }
}